// Round 14
// baseline (507.136 us; speedup 1.0000x reference)
//
#include <hip/hip_runtime.h>

// ---------------------------------------------------------------------------
// MultiHeadAttention: x(4,2048,512) fp32, adj(4,2048,2048) 0/1 fp32
// R25: single persistent kernel, manual device-scope spin barriers (R24's
// hipLaunchCooperativeKernel is NOT graph-capturable -> outputs untouched).
// 512 blocks x 256 thr, __launch_bounds__(256,2): exactly 2 blocks/CU, LDS
// max-phase 40KB (80/160 per CU), so all blocks co-resident -> barrier safe.
// Phases (bodies verbatim R21, best 199.6us):
//   prep(14 units/blk) -> bar -> gemm0(tiles blk, blk+512) -> bar ->
//   attn(1:1) -> bar -> gemm1(tiles blk, blk+512)
// Barrier: __threadfence (agent fence: cross-XCD L2 wb/inv) + device atomic
// + t0 spin to 512. Counters in ws dead gap, zeroed by hipMemsetAsync.
// Deletes 3 launch gaps (~20-35us per R14 accounting).
// ---------------------------------------------------------------------------

typedef __attribute__((ext_vector_type(8))) short bf16x8;
typedef __attribute__((ext_vector_type(4))) float f32x4;
typedef __attribute__((ext_vector_type(4))) unsigned short ushort4v;
typedef __attribute__((ext_vector_type(4))) _Float16 f16x4;
typedef __attribute__((ext_vector_type(8))) _Float16 f16x8;
typedef __attribute__((ext_vector_type(2))) __fp16 h16x2;  // cvt_pkrtz return type
typedef __attribute__((ext_vector_type(2))) unsigned long long u64x2;

#if __has_builtin(__builtin_amdgcn_exp2f)
#define EXP2F(x) __builtin_amdgcn_exp2f(x)
#else
#define EXP2F(x) exp2f(x)
#endif

// 0.125 (1/sqrt(64)) * log2(e), folded into Q at the QKV-gemm epilogue
#define QSCALE 0.18033688011112042f

__device__ __forceinline__ unsigned short f2bf(float f) {
  unsigned int u = __float_as_uint(f);
  u += 0x7FFFu + ((u >> 16) & 1u);
  return (unsigned short)(u >> 16);
}
__device__ __forceinline__ unsigned short f2h(float f) {
  union { _Float16 h; unsigned short u; } cv;
  cv.h = (_Float16)f;
  return cv.u;
}

// sign-extend bit (pos) of w to 0 / 0xFFFFFFFF
__device__ __forceinline__ int sbit(unsigned w, int pos) {
  return ((int)(w << (31 - pos))) >> 31;  // compiler emits v_bfe_i32
}

// pack 8 floats -> f16x8 via 4 packed RTZ converts
__device__ __forceinline__ f16x8 pk8(const float* p) {
  union { struct { h16x2 a, b, c, d; } s; f16x8 v; } u;
  u.s.a = __builtin_amdgcn_cvt_pkrtz(p[0], p[1]);
  u.s.b = __builtin_amdgcn_cvt_pkrtz(p[2], p[3]);
  u.s.c = __builtin_amdgcn_cvt_pkrtz(p[4], p[5]);
  u.s.d = __builtin_amdgcn_cvt_pkrtz(p[6], p[7]);
  return u.v;
}

// PV matmul: K=32 f16 (slot pairing identical in A and B, so a two-K=16
// fallback is mathematically identical if the builtin is absent)
__device__ __forceinline__ f32x4 mfma_pv(f16x8 a, f16x8 b, f32x4 c) {
#if __has_builtin(__builtin_amdgcn_mfma_f32_16x16x32_f16)
  return __builtin_amdgcn_mfma_f32_16x16x32_f16(a, b, c, 0, 0, 0);
#else
  union { f16x8 v; struct { f16x4 lo, hi; } s; } ua, ub;
  ua.v = a; ub.v = b;
  c = __builtin_amdgcn_mfma_f32_16x16x16f16(ua.s.lo, ub.s.lo, c, 0, 0, 0);
  return __builtin_amdgcn_mfma_f32_16x16x16f16(ua.s.hi, ub.s.hi, c, 0, 0, 0);
#endif
}

// device-scope grid barrier: counter pre-zeroed per launch (hipMemsetAsync)
__device__ __forceinline__ void gridbar(unsigned* c) {
  __syncthreads();
  if (threadIdx.x == 0) {
    __threadfence();  // agent-scope release (cross-XCD L2 writeback)
    __hip_atomic_fetch_add(c, 1u, __ATOMIC_RELEASE, __HIP_MEMORY_SCOPE_AGENT);
    while (__hip_atomic_load(c, __ATOMIC_ACQUIRE, __HIP_MEMORY_SCOPE_AGENT) < 512u)
      __builtin_amdgcn_s_sleep(8);
    __threadfence();  // agent-scope acquire (L2 invalidate)
  }
  __syncthreads();
}

union ShMem {
  struct { unsigned short A[2][128][40], B[2][128][40]; } g0;  // 40 KB (gemm0)
  unsigned short T[64][136];                                   // V-transpose staging
  struct { unsigned short K[2][64][64], V[2][64][64]; } at;    // 32 KB (attn)
  struct { unsigned short A[2][64][40], B[2][64][40]; } g1;    // 20 KB (gemm1)
};

// ===========================================================================
__global__ __launch_bounds__(256, 2) void fused_all(
    const float* x, unsigned short* x_bf, const float* wqkv, unsigned short* wqkv_bf,
    const float* outw, unsigned short* outw_bf, const float* adj,
    unsigned long long* abits, const float* bqkv, unsigned short* Qb,
    unsigned short* Kb, unsigned short* Vb, unsigned short* Ob,
    const float* outb, float* out, unsigned* ctr) {
  __shared__ ShMem sh;

  const int t = threadIdx.x;
  const int blk = blockIdx.x;
  const int lane = t & 63, w = t >> 6, ln = lane & 15, quad = lane >> 4;

  // ================= phase 0: prep (7168 units over 512 blocks) ==============
#pragma unroll 1
  for (int i = 0; i < 14; ++i) {
    const int bid = blk + i * 512;
    if (bid < 5120) {
      const float* in; unsigned short* outp; int idx;
      if (bid < 4096) { in = x; outp = x_bf; idx = bid * 256 + t; }
      else if (bid < 4864) { in = wqkv; outp = wqkv_bf; idx = (bid - 4096) * 256 + t; }
      else { in = outw; outp = outw_bf; idx = (bid - 4864) * 256 + t; }
      float4 v = ((const float4*)in)[idx];
      ushort4v o;
      o[0] = f2bf(v.x); o[1] = f2bf(v.y); o[2] = f2bf(v.z); o[3] = f2bf(v.w);
      ((ushort4v*)outp)[idx] = o;
    } else {
      // adj -> ballot-natural masks: [b][it(8)][q][4]; W_c bit l = adj[q][256it+4l+c]
      const int gw = (bid - 5120) * 4 + (t >> 6);  // 0..8191 = b*2048+q
      const int l = t & 63;
      const int b = gw >> 11, q = gw & 2047;
      const float4* row = (const float4*)(adj + ((size_t)b * 2048 + q) * 2048) + l;
      unsigned long long* ob = abits + ((size_t)b * 8 * 2048 + q) * 4;
#pragma unroll
      for (int it = 0; it < 8; ++it) {
        const float4 v = row[(size_t)it * 64];
        const unsigned long long w0 = __ballot(v.x != 0.f);
        const unsigned long long w1 = __ballot(v.y != 0.f);
        const unsigned long long w2 = __ballot(v.z != 0.f);
        const unsigned long long w3 = __ballot(v.w != 0.f);
        if (l == 0) {
          ob[(size_t)it * 8192 + 0] = w0;
          ob[(size_t)it * 8192 + 1] = w1;
          ob[(size_t)it * 8192 + 2] = w2;
          ob[(size_t)it * 8192 + 3] = w3;
        }
      }
    }
  }

  gridbar(ctr + 0);

  // ================= phase 1: gemm0 (768 tiles: blk, blk+512) ================
#pragma unroll 1
  for (int rep = 0; rep < 2; ++rep) {
    const int bid = blk + rep * 512;
    if (bid >= 768) break;
    __syncthreads();  // LDS reuse across reps/phases

    const int Ntiles = 12, Kdim = 512;
    const int xcd = bid & 7, loc = bid >> 3;
    const int mt = xcd * 8 + loc / Ntiles;  // 96 groups / 12
    const int nt = loc % Ntiles;
    const int wm = (w >> 1) * 64, wn = (w & 1) * 64;
    const int strow = t >> 2, stcol = (t & 3) * 8;

    const unsigned short* A = x_bf;
    const unsigned short* Bt = wqkv_bf;

    const size_t abase = (size_t)(mt * 128 + strow) * Kdim + stcol;
    const size_t bbase = (size_t)(nt * 128 + strow) * Kdim + stcol;

    f32x4 acc[4][4];
#pragma unroll
    for (int i = 0; i < 4; ++i)
#pragma unroll
      for (int j = 0; j < 4; ++j) acc[i][j] = (f32x4){0.f, 0.f, 0.f, 0.f};

    bf16x8 a0 = *(const bf16x8*)(A + abase);
    bf16x8 a1 = *(const bf16x8*)(A + abase + (size_t)64 * Kdim);
    bf16x8 b0 = *(const bf16x8*)(Bt + bbase);
    bf16x8 b1 = *(const bf16x8*)(Bt + bbase + (size_t)64 * Kdim);
    *(bf16x8*)&sh.g0.A[0][strow][stcol] = a0;
    *(bf16x8*)&sh.g0.A[0][64 + strow][stcol] = a1;
    *(bf16x8*)&sh.g0.B[0][strow][stcol] = b0;
    *(bf16x8*)&sh.g0.B[0][64 + strow][stcol] = b1;
    __syncthreads();

    for (int it = 0; it < 16; ++it) {
      const int cur = it & 1, nxt = cur ^ 1;

      const int kn = ((it + 1) << 5) & (Kdim - 1);
      a0 = *(const bf16x8*)(A + abase + kn);
      a1 = *(const bf16x8*)(A + abase + (size_t)64 * Kdim + kn);
      b0 = *(const bf16x8*)(Bt + bbase + kn);
      b1 = *(const bf16x8*)(Bt + bbase + (size_t)64 * Kdim + kn);

      bf16x8 bfr[4];
#pragma unroll
      for (int nf = 0; nf < 4; ++nf)
        bfr[nf] = *(const bf16x8*)&sh.g0.B[cur][wn + nf * 16 + ln][quad * 8];
#pragma unroll
      for (int mf = 0; mf < 4; ++mf) {
        bf16x8 af = *(const bf16x8*)&sh.g0.A[cur][wm + mf * 16 + ln][quad * 8];
#pragma unroll
        for (int nf = 0; nf < 4; ++nf)
          acc[mf][nf] = __builtin_amdgcn_mfma_f32_16x16x32_bf16(af, bfr[nf], acc[mf][nf], 0, 0, 0);
      }

      if (it + 1 < 16) {
        *(bf16x8*)&sh.g0.A[nxt][strow][stcol] = a0;
        *(bf16x8*)&sh.g0.A[nxt][64 + strow][stcol] = a1;
        *(bf16x8*)&sh.g0.B[nxt][strow][stcol] = b0;
        *(bf16x8*)&sh.g0.B[nxt][64 + strow][stcol] = b1;
        __syncthreads();
      }
    }

    // epilogue (C layout: col=lane&15, row=quad*4+reg)
    if (nt >= 8) {
      // V: LDS transpose -> coalesced V^T rows. Tile = 128 s x 128 d-cols.
      const int bb = mt >> 4, sq0 = (mt & 15) * 128;
#pragma unroll
      for (int half = 0; half < 2; ++half) {
        __syncthreads();  // A/B buffers dead; T aliases them
        if ((w & 1) == half) {
#pragma unroll
          for (int nf = 0; nf < 4; ++nf) {
            const float bv = bqkv[nt * 128 + half * 64 + nf * 16 + ln];
#pragma unroll
            for (int mf = 0; mf < 4; ++mf)
#pragma unroll
              for (int r = 0; r < 4; ++r)
                sh.T[nf * 16 + ln][wm + mf * 16 + quad * 4 + r] = f2h(acc[mf][nf][r] + bv);
          }
        }
        __syncthreads();
#pragma unroll
        for (int rep2 = 0; rep2 < 4; ++rep2) {
          const int row = rep2 * 16 + (t >> 4), c = t & 15;
          const bf16x8 val = *(const bf16x8*)&sh.T[row][c * 8];
          const int hd = (nt - 8) * 128 + half * 64 + row;
          const int hh = hd >> 6, dd = hd & 63;
          *(bf16x8*)(Vb + ((size_t)(bb * 8 + hh) * 64 + dd) * 2048 + sq0 + c * 8) = val;
        }
      }
    } else {
#pragma unroll
      for (int mf = 0; mf < 4; ++mf) {
        const int m = mt * 128 + wm + mf * 16 + quad * 4;
#pragma unroll
        for (int nf = 0; nf < 4; ++nf) {
          const int n = nt * 128 + wn + nf * 16 + ln;
          const float bv = bqkv[n];
          const int hd = n & 511;
          const int hh = hd >> 6, dd = hd & 63;
          const int bb = m >> 11, sq = m & 2047;
          if (n < 512) {
#pragma unroll
            for (int r = 0; r < 4; ++r)
              Qb[((size_t)(bb * 8 + hh) * 2048 + sq + r) * 64 + dd] =
                  f2bf((acc[mf][nf][r] + bv) * QSCALE);
          } else {
#pragma unroll
            for (int r = 0; r < 4; ++r)
              Kb[((size_t)(bb * 8 + hh) * 2048 + sq + r) * 64 + dd] = f2bf(acc[mf][nf][r] + bv);
          }
        }
      }
    }
  }

  gridbar(ctr + 1);

  // ================= phase 2: attn (1:1, verbatim R21) =======================
  {
    const int bh = blk & 31, qt = blk >> 5, bb = bh >> 3;
    const int sbase = qt * 128;

    const unsigned short* Qp = Qb + (size_t)bh * (2048 * 64);
    const unsigned short* Kp = Kb + (size_t)bh * (2048 * 64);
    const unsigned short* Vp = Vb + (size_t)bh * (64 * 2048);
    const unsigned long long* Mb = abits + ((size_t)bb * 8 * 2048 + sbase + w * 32 + ln) * 4;

    bf16x8 qf[2][2];
#pragma unroll
    for (int qg = 0; qg < 2; ++qg) {
      const int qrow = sbase + w * 32 + qg * 16 + ln;
      qf[qg][0] = *(const bf16x8*)(Qp + (size_t)qrow * 64 + quad * 8);
      qf[qg][1] = *(const bf16x8*)(Qp + (size_t)qrow * 64 + 32 + quad * 8);
    }

    const _Float16 one_h = (_Float16)((ln == 0) ? 1.0f : 0.0f);
    const f16x8 vf_one = (f16x8){one_h, one_h, one_h, one_h, one_h, one_h, one_h, one_h};

    const f32x4 zf = (f32x4){0.f, 0.f, 0.f, 0.f};

    f32x4 acc_o[2][4];
#pragma unroll
    for (int qg = 0; qg < 2; ++qg)
#pragma unroll
      for (int dg = 0; dg < 4; ++dg) acc_o[qg][dg] = zf;
    f32x4 acc_1[2] = {zf, zf};

    const int strow = t >> 2;
    const int stcol = (t & 3) * 16;
    const int c0 = (t & 3) * 2;
    const int gkw = (strow & 3) | (((strow >> 3) & 1) << 2);
    const int gvw = strow & 7;

    const unsigned short* Kl = Kp + (size_t)strow * 64 + stcol;
    const unsigned short* Vl = Vp + (size_t)strow * 2048 + stcol;

    bf16x8 kr0 = *(const bf16x8*)(Kl);
    bf16x8 kr1 = *(const bf16x8*)(Kl + 8);
    bf16x8 vr0 = *(const bf16x8*)(Vl);
    bf16x8 vr1 = *(const bf16x8*)(Vl + 8);
    *(bf16x8*)&sh.at.K[0][strow][(c0 ^ gkw) << 3] = kr0;
    *(bf16x8*)&sh.at.K[0][strow][((c0 + 1) ^ gkw) << 3] = kr1;
    *(bf16x8*)&sh.at.V[0][strow][(c0 ^ gvw) << 3] = vr0;
    *(bf16x8*)&sh.at.V[0][strow][((c0 + 1) ^ gvw) << 3] = vr1;
    u64x2 Wlo[2], Whi[2];
#pragma unroll
    for (int qg = 0; qg < 2; ++qg) {
      Wlo[qg] = *(const u64x2*)(Mb + qg * 64);
      Whi[qg] = *(const u64x2*)(Mb + qg * 64 + 2);
    }
    __syncthreads();

    const int kperm = ((ln >> 2) << 3) + (ln & 3);
    const int gkr = (ln & 3) | (((ln >> 2) & 1) << 2);
    const int gvr = ln & 7;
    const int kc = (quad ^ gkr) << 3;
    const unsigned q2 = quad << 1;

    for (int kts = 0; kts < 8; ++kts) {
      const size_t itn = (size_t)((kts < 7) ? kts + 1 : 0) * 8192;
      u64x2 nWlo[2], nWhi[2];
#pragma unroll
      for (int qg = 0; qg < 2; ++qg) {
        nWlo[qg] = *(const u64x2*)(Mb + itn + qg * 64);
        nWhi[qg] = *(const u64x2*)(Mb + itn + qg * 64 + 2);
      }

#pragma unroll
      for (int j = 0; j < 4; ++j) {
        const int kt = kts * 4 + j;
        const int cur = j & 1, nxt = cur ^ 1;

        kr0 = *(const bf16x8*)(Kl + (size_t)(kt + 1) * 4096);
        kr1 = *(const bf16x8*)(Kl + (size_t)(kt + 1) * 4096 + 8);
        vr0 = *(const bf16x8*)(Vl + (kt + 1) * 64);
        vr1 = *(const bf16x8*)(Vl + (kt + 1) * 64 + 8);

        f32x4 sc[2][4];
        __builtin_amdgcn_s_setprio(1);
#pragma unroll
        for (int h = 0; h < 2; ++h)
#pragma unroll
          for (int e = 0; e < 2; ++e) {
            const int krow = h * 32 + kperm + e * 4;
            bf16x8 kf0 = *(const bf16x8*)&sh.at.K[cur][krow][kc];
            bf16x8 kf1 = *(const bf16x8*)&sh.at.K[cur][krow][kc ^ 32];
#pragma unroll
            for (int qg = 0; qg < 2; ++qg) {
              f32x4 z = __builtin_amdgcn_mfma_f32_16x16x32_bf16(kf0, qf[qg][0], zf, 0, 0, 0);
              sc[qg][h * 2 + e] =
                  __builtin_amdgcn_mfma_f32_16x16x32_bf16(kf1, qf[qg][1], z, 0, 0, 0);
            }
          }
        __builtin_amdgcn_s_setprio(0);

        f16x8 vfa[2][4];
#pragma unroll
        for (int h = 0; h < 2; ++h)
#pragma unroll
          for (int dg = 0; dg < 4; ++dg)
            vfa[h][dg] = *(const f16x8*)&sh.at.V[cur][dg * 16 + ln][((h * 4 + quad) ^ gvr) << 3];

        f16x8 pa[2][2];
#pragma unroll
        for (int qg = 0; qg < 2; ++qg) {
          const unsigned s0 = (unsigned)(Wlo[qg][0] >> (j >= 2 ? 32 : 0)) >> q2;
          const unsigned s1 = (unsigned)(Wlo[qg][1] >> (j >= 2 ? 32 : 0)) >> q2;
          const unsigned s2 = (unsigned)(Whi[qg][0] >> (j >= 2 ? 32 : 0)) >> q2;
          const unsigned s3 = (unsigned)(Whi[qg][1] >> (j >= 2 ? 32 : 0)) >> q2;
#pragma unroll
          for (int h = 0; h < 2; ++h) {
            float p[8];
#pragma unroll
            for (int e = 0; e < 2; ++e) {
              const int pos = (j & 1) * 16 + h * 8 + e;
              p[e * 4 + 0] =
                  EXP2F(__int_as_float(__float_as_int(sc[qg][h * 2 + e][0]) & sbit(s0, pos)));
              p[e * 4 + 1] =
                  EXP2F(__int_as_float(__float_as_int(sc[qg][h * 2 + e][1]) & sbit(s1, pos)));
              p[e * 4 + 2] =
                  EXP2F(__int_as_float(__float_as_int(sc[qg][h * 2 + e][2]) & sbit(s2, pos)));
              p[e * 4 + 3] =
                  EXP2F(__int_as_float(__float_as_int(sc[qg][h * 2 + e][3]) & sbit(s3, pos)));
            }
            pa[qg][h] = pk8(p);
          }
        }

        __builtin_amdgcn_s_setprio(1);
#pragma unroll
        for (int h = 0; h < 2; ++h)
#pragma unroll
          for (int qg = 0; qg < 2; ++qg) {
#pragma unroll
            for (int dg = 0; dg < 4; ++dg)
              acc_o[qg][dg] = mfma_pv(pa[qg][h], vfa[h][dg], acc_o[qg][dg]);
            acc_1[qg] = mfma_pv(pa[qg][h], vf_one, acc_1[qg]);
          }
        __builtin_amdgcn_s_setprio(0);

        if (kt < 31) {
          *(bf16x8*)&sh.at.K[nxt][strow][(c0 ^ gkw) << 3] = kr0;
          *(bf16x8*)&sh.at.K[nxt][strow][((c0 + 1) ^ gkw) << 3] = kr1;
          *(bf16x8*)&sh.at.V[nxt][strow][(c0 ^ gvw) << 3] = vr0;
          *(bf16x8*)&sh.at.V[nxt][strow][((c0 + 1) ^ gvw) << 3] = vr1;
          __syncthreads();
        }
      }
      Wlo[0] = nWlo[0]; Wlo[1] = nWlo[1];
      Whi[0] = nWhi[0]; Whi[1] = nWhi[1];
    }

    // epilogue: lsum for row q=quad*4+r lives in acc_1[qg][r] at lanes ln==0
    unsigned short* Op = Ob + (size_t)bb * 2048 * 512 + (size_t)(bh & 7) * 64;
#pragma unroll
    for (int qg = 0; qg < 2; ++qg)
#pragma unroll
      for (int r = 0; r < 4; ++r) {
        const float inv = 1.0f / __shfl(acc_1[qg][r], quad * 16);
        const int sq = sbase + w * 32 + qg * 16 + quad * 4 + r;
#pragma unroll
        for (int dg = 0; dg < 4; ++dg)
          Op[(size_t)sq * 512 + dg * 16 + ln] = f2bf(acc_o[qg][dg][r] * inv);
      }
  }

  gridbar(ctr + 2);

  // ================= phase 3: gemm1 (1024 tiles: blk, blk+512) ===============
#pragma unroll 1
  for (int rep = 0; rep < 2; ++rep) {
    const int bid = blk + rep * 512;
    __syncthreads();  // LDS reuse

    const int xcd = bid & 7, loc = bid >> 3;  // loc 0..127
    const int mt = xcd * 16 + (loc >> 3);     // 0..127
    const int nt = loc & 7;                   // 0..7
    const int wm = (w >> 1) * 32, wn = (w & 1) * 32;
    const int strow = t >> 2, stcol = (t & 3) * 8;

    const size_t abase = (size_t)(mt * 64 + strow) * 512 + stcol;
    const size_t bbase = (size_t)(nt * 64 + strow) * 512 + stcol;

    f32x4 acc[2][2];
#pragma unroll
    for (int i = 0; i < 2; ++i)
#pragma unroll
      for (int j = 0; j < 2; ++j) acc[i][j] = (f32x4){0.f, 0.f, 0.f, 0.f};

    bf16x8 a0 = *(const bf16x8*)(Ob + abase);
    bf16x8 b0 = *(const bf16x8*)(outw_bf + bbase);
    *(bf16x8*)&sh.g1.A[0][strow][stcol] = a0;
    *(bf16x8*)&sh.g1.B[0][strow][stcol] = b0;
    __syncthreads();

    for (int it = 0; it < 16; ++it) {
      const int cur = it & 1, nxt = cur ^ 1;

      const int kn = ((it + 1) << 5) & 511;
      a0 = *(const bf16x8*)(Ob + abase + kn);
      b0 = *(const bf16x8*)(outw_bf + bbase + kn);

      bf16x8 bfr[2];
#pragma unroll
      for (int nf = 0; nf < 2; ++nf)
        bfr[nf] = *(const bf16x8*)&sh.g1.B[cur][wn + nf * 16 + ln][quad * 8];
#pragma unroll
      for (int mf = 0; mf < 2; ++mf) {
        bf16x8 af = *(const bf16x8*)&sh.g1.A[cur][wm + mf * 16 + ln][quad * 8];
#pragma unroll
        for (int nf = 0; nf < 2; ++nf)
          acc[mf][nf] = __builtin_amdgcn_mfma_f32_16x16x32_bf16(af, bfr[nf], acc[mf][nf], 0, 0, 0);
      }

      if (it + 1 < 16) {
        *(bf16x8*)&sh.g1.A[nxt][strow][stcol] = a0;
        *(bf16x8*)&sh.g1.B[nxt][strow][stcol] = b0;
        __syncthreads();
      }
    }

    // epilogue (C layout: col=lane&15, row=quad*4+reg)
#pragma unroll
    for (int mf = 0; mf < 2; ++mf) {
      const int m = mt * 64 + wm + mf * 16 + quad * 4;
#pragma unroll
      for (int nf = 0; nf < 2; ++nf) {
        const int n = nt * 64 + wn + nf * 16 + ln;
        const float bv = outb[n];
#pragma unroll
        for (int r = 0; r < 4; ++r) out[(size_t)(m + r) * 512 + n] = acc[mf][nf][r] + bv;
      }
    }
  }
}

// ---------------------------------------------------------------------------
extern "C" void kernel_launch(void* const* d_in, const int* in_sizes, int n_in, void* d_out,
                              int out_size, void* d_ws, size_t ws_size, hipStream_t stream) {
  const float* x = (const float*)d_in[0];
  const float* adj = (const float*)d_in[1];
  const float* wqkv = (const float*)d_in[2];
  const float* bqkv = (const float*)d_in[3];
  const float* outw = (const float*)d_in[4];
  const float* outb = (const float*)d_in[5];
  float* out = (float*)d_out;

  char* ws = (char*)d_ws;
  unsigned short* x_bf = (unsigned short*)(ws);                      //  8.0 MB
  unsigned short* wqkv_bf = (unsigned short*)(ws + 8388608);         //  1.5 MB
  unsigned short* outw_bf = (unsigned short*)(ws + 9961472);         //  0.5 MB
  unsigned long long* abits = (unsigned long long*)(ws + 10485760);  //  2.0 MB [b][it][q][4]
  unsigned* ctr = (unsigned*)(ws + 25165824);                        //  barrier counters
  unsigned short* Qb = (unsigned short*)(ws + 27262976);             //  8.0 MB (b,h,s,d) bf16
  unsigned short* Kb = (unsigned short*)(ws + 35651584);             //  8.0 MB (b,h,s,d) bf16
  unsigned short* Vb = (unsigned short*)(ws + 44040192);             //  8.0 MB (b,h,d,s) f16
  unsigned short* Ob = (unsigned short*)(ws + 52428800);             //  8.0 MB (b,s,e) bf16

  hipMemsetAsync(ctr, 0, 64, stream);

  fused_all<<<512, 256, 0, stream>>>(x, x_bf, wqkv, wqkv_bf, outw, outw_bf, adj, abits,
                                     bqkv, Qb, Kb, Vb, Ob, outb, out, ctr);
}

// Round 15
// 198.854 us; speedup vs baseline: 2.5503x; 2.5503x over previous
//
#include <hip/hip_runtime.h>

// ---------------------------------------------------------------------------
// MultiHeadAttention: x(4,2048,512) fp32, adj(4,2048,2048) 0/1 fp32
// R26 = R21 verbatim (best measured: 199.6us) — restore after the R24/R25
// fusion experiments. Conclusions locked in across R12-R25:
//  - attn (50.2us) is at the structural floor of this decomposition: the
//    ~28% no-issue time is the intra-iter QK->mask/exp->PV dep chain (R22
//    barrier-halving + 2-deep prefetch: no change; R14 2x occupancy: +5%;
//    R16 half LDS traffic: neutral; R15 no-LDS: 2.5x worse).
//  - prep/gemm0/gemm1 all < attn (absent from top-5); gemm TLP saturated
//    (R21 512blk win; R23 1024blk neutral).
//  - inter-dispatch time (~40-70us) is NOT removable here: co-resident
//    fusion thrashes L2 (R18/R20), hipLaunchCooperativeKernel is not
//    graph-capturable (R24 silent no-op), manual spin barriers flush L2
//    per-block via agent fences (R25: +300us).
// Pipeline: prep(7168) -> gemm128(768) -> attn(512) -> gemm64(512).
// ---------------------------------------------------------------------------

typedef __attribute__((ext_vector_type(8))) short bf16x8;
typedef __attribute__((ext_vector_type(4))) float f32x4;
typedef __attribute__((ext_vector_type(4))) unsigned short ushort4v;
typedef __attribute__((ext_vector_type(4))) _Float16 f16x4;
typedef __attribute__((ext_vector_type(8))) _Float16 f16x8;
typedef __attribute__((ext_vector_type(2))) __fp16 h16x2;  // cvt_pkrtz return type
typedef __attribute__((ext_vector_type(2))) unsigned long long u64x2;

#if __has_builtin(__builtin_amdgcn_exp2f)
#define EXP2F(x) __builtin_amdgcn_exp2f(x)
#else
#define EXP2F(x) exp2f(x)
#endif

// 0.125 (1/sqrt(64)) * log2(e), folded into Q at the QKV-gemm epilogue
#define QSCALE 0.18033688011112042f

__device__ __forceinline__ unsigned short f2bf(float f) {
  unsigned int u = __float_as_uint(f);
  u += 0x7FFFu + ((u >> 16) & 1u);
  return (unsigned short)(u >> 16);
}
__device__ __forceinline__ unsigned short f2h(float f) {
  union { _Float16 h; unsigned short u; } cv;
  cv.h = (_Float16)f;
  return cv.u;
}

// sign-extend bit (pos) of w to 0 / 0xFFFFFFFF
__device__ __forceinline__ int sbit(unsigned w, int pos) {
  return ((int)(w << (31 - pos))) >> 31;  // compiler emits v_bfe_i32
}

// pack 8 floats -> f16x8 via 4 packed RTZ converts
__device__ __forceinline__ f16x8 pk8(const float* p) {
  union { struct { h16x2 a, b, c, d; } s; f16x8 v; } u;
  u.s.a = __builtin_amdgcn_cvt_pkrtz(p[0], p[1]);
  u.s.b = __builtin_amdgcn_cvt_pkrtz(p[2], p[3]);
  u.s.c = __builtin_amdgcn_cvt_pkrtz(p[4], p[5]);
  u.s.d = __builtin_amdgcn_cvt_pkrtz(p[6], p[7]);
  return u.v;
}

// PV matmul: K=32 f16 (slot pairing identical in A and B, so a two-K=16
// fallback is mathematically identical if the builtin is absent)
__device__ __forceinline__ f32x4 mfma_pv(f16x8 a, f16x8 b, f32x4 c) {
#if __has_builtin(__builtin_amdgcn_mfma_f32_16x16x32_f16)
  return __builtin_amdgcn_mfma_f32_16x16x32_f16(a, b, c, 0, 0, 0);
#else
  union { f16x8 v; struct { f16x4 lo, hi; } s; } ua, ub;
  ua.v = a; ub.v = b;
  c = __builtin_amdgcn_mfma_f32_16x16x16f16(ua.s.lo, ub.s.lo, c, 0, 0, 0);
  return __builtin_amdgcn_mfma_f32_16x16x16f16(ua.s.hi, ub.s.hi, c, 0, 0, 0);
#endif
}

// ---------------- fused prep: casts + adj bit-pack, one launch ---------------
__global__ __launch_bounds__(256) void prep_k(const float* __restrict__ x,
                                              unsigned short* __restrict__ x_bf,
                                              const float* __restrict__ wqkv,
                                              unsigned short* __restrict__ wqkv_bf,
                                              const float* __restrict__ outw,
                                              unsigned short* __restrict__ outw_bf,
                                              const float* __restrict__ adj,
                                              unsigned long long* __restrict__ abits) {
  const int bid = blockIdx.x;
  if (bid < 5120) {
    const float* in; unsigned short* out; int i;
    if (bid < 4096) { in = x; out = x_bf; i = bid * 256 + threadIdx.x; }
    else if (bid < 4864) { in = wqkv; out = wqkv_bf; i = (bid - 4096) * 256 + threadIdx.x; }
    else { in = outw; out = outw_bf; i = (bid - 4864) * 256 + threadIdx.x; }
    float4 v = ((const float4*)in)[i];
    ushort4v o;
    o[0] = f2bf(v.x); o[1] = f2bf(v.y); o[2] = f2bf(v.z); o[3] = f2bf(v.w);
    ((ushort4v*)out)[i] = o;
  } else {
    // adj -> ballot-natural masks: [b][it(8)][q][4]; W_c bit l = adj[q][256it+4l+c]
    const int gw = (bid - 5120) * 4 + (threadIdx.x >> 6);  // 0..8191 = b*2048+q
    const int l = threadIdx.x & 63;
    const int b = gw >> 11, q = gw & 2047;
    const float4* row = (const float4*)(adj + ((size_t)b * 2048 + q) * 2048) + l;
    unsigned long long* ob = abits + ((size_t)b * 8 * 2048 + q) * 4;
#pragma unroll
    for (int it = 0; it < 8; ++it) {
      const float4 v = row[(size_t)it * 64];
      const unsigned long long w0 = __ballot(v.x != 0.f);
      const unsigned long long w1 = __ballot(v.y != 0.f);
      const unsigned long long w2 = __ballot(v.z != 0.f);
      const unsigned long long w3 = __ballot(v.w != 0.f);
      if (l == 0) {
        ob[(size_t)it * 8192 + 0] = w0;
        ob[(size_t)it * 8192 + 1] = w1;
        ob[(size_t)it * 8192 + 2] = w2;
        ob[(size_t)it * 8192 + 3] = w3;
      }
    }
  }
}

// ---------------- 128x128 bf16 MFMA GEMM (QKV projection) --------------------
// XCD-local tiling: blk&7 = XCD. Double-buffered LDS, one barrier/iter.
// Epilogue: Q scaled bf16 / K bf16 / V f16 LDS-transposed.
__global__ __launch_bounds__(256, 3) void gemm128_k(const unsigned short* __restrict__ A,
                                                    const unsigned short* __restrict__ Bt,
                                                    const float* __restrict__ bias, int Kdim,
                                                    int Ntiles, unsigned short* __restrict__ q_out,
                                                    unsigned short* __restrict__ k_out,
                                                    unsigned short* __restrict__ v_out) {
  __shared__ union {
    struct { unsigned short A[2][128][40], B[2][128][40]; } s;  // 40 KB
    unsigned short T[64][136];                                  // V-transpose staging
  } u;

  const int t = threadIdx.x;
  const int lane = t & 63, w = t >> 6, ln = lane & 15, quad = lane >> 4;
  const int xcd = blockIdx.x & 7, loc = blockIdx.x >> 3;
  const int mt = xcd * ((gridDim.x >> 3) / Ntiles) + loc / Ntiles;
  const int nt = loc % Ntiles;
  const int wm = (w >> 1) * 64, wn = (w & 1) * 64;
  const int strow = t >> 2, stcol = (t & 3) * 8;

  const size_t abase = (size_t)(mt * 128 + strow) * Kdim + stcol;
  const size_t bbase = (size_t)(nt * 128 + strow) * Kdim + stcol;

  f32x4 acc[4][4];
#pragma unroll
  for (int i = 0; i < 4; ++i)
#pragma unroll
    for (int j = 0; j < 4; ++j) acc[i][j] = (f32x4){0.f, 0.f, 0.f, 0.f};

  // prologue: load + stage chunk 0 into buf 0
  bf16x8 a0 = *(const bf16x8*)(A + abase);
  bf16x8 a1 = *(const bf16x8*)(A + abase + (size_t)64 * Kdim);
  bf16x8 b0 = *(const bf16x8*)(Bt + bbase);
  bf16x8 b1 = *(const bf16x8*)(Bt + bbase + (size_t)64 * Kdim);
  *(bf16x8*)&u.s.A[0][strow][stcol] = a0;
  *(bf16x8*)&u.s.A[0][64 + strow][stcol] = a1;
  *(bf16x8*)&u.s.B[0][strow][stcol] = b0;
  *(bf16x8*)&u.s.B[0][64 + strow][stcol] = b1;
  __syncthreads();

  const int iters = Kdim >> 5;
  for (int it = 0; it < iters; ++it) {
    const int cur = it & 1, nxt = cur ^ 1;

    const int kn = ((it + 1) << 5) & (Kdim - 1);
    a0 = *(const bf16x8*)(A + abase + kn);
    a1 = *(const bf16x8*)(A + abase + (size_t)64 * Kdim + kn);
    b0 = *(const bf16x8*)(Bt + bbase + kn);
    b1 = *(const bf16x8*)(Bt + bbase + (size_t)64 * Kdim + kn);

    bf16x8 bfr[4];
#pragma unroll
    for (int nf = 0; nf < 4; ++nf)
      bfr[nf] = *(const bf16x8*)&u.s.B[cur][wn + nf * 16 + ln][quad * 8];
#pragma unroll
    for (int mf = 0; mf < 4; ++mf) {
      bf16x8 af = *(const bf16x8*)&u.s.A[cur][wm + mf * 16 + ln][quad * 8];
#pragma unroll
      for (int nf = 0; nf < 4; ++nf)
        acc[mf][nf] = __builtin_amdgcn_mfma_f32_16x16x32_bf16(af, bfr[nf], acc[mf][nf], 0, 0, 0);
    }

    if (it + 1 < iters) {
      *(bf16x8*)&u.s.A[nxt][strow][stcol] = a0;
      *(bf16x8*)&u.s.A[nxt][64 + strow][stcol] = a1;
      *(bf16x8*)&u.s.B[nxt][strow][stcol] = b0;
      *(bf16x8*)&u.s.B[nxt][64 + strow][stcol] = b1;
      __syncthreads();
    }
  }

  // ---------------- epilogue (C layout: col=lane&15, row=quad*4+reg) ----------
  if (nt >= 8) {
    // V: LDS transpose -> coalesced V^T rows. Tile = 128 s x 128 d-cols.
    const int bb = mt >> 4, sq0 = (mt & 15) * 128;
#pragma unroll
    for (int half = 0; half < 2; ++half) {
      __syncthreads();  // A/B buffers dead; T aliases them
      if ((w & 1) == half) {
#pragma unroll
        for (int nf = 0; nf < 4; ++nf) {
          const float bv = bias[nt * 128 + half * 64 + nf * 16 + ln];
#pragma unroll
          for (int mf = 0; mf < 4; ++mf)
#pragma unroll
            for (int r = 0; r < 4; ++r)
              u.T[nf * 16 + ln][wm + mf * 16 + quad * 4 + r] = f2h(acc[mf][nf][r] + bv);
        }
      }
      __syncthreads();
#pragma unroll
      for (int rep = 0; rep < 4; ++rep) {
        const int row = rep * 16 + (t >> 4), c = t & 15;
        const bf16x8 val = *(const bf16x8*)&u.T[row][c * 8];
        const int hd = (nt - 8) * 128 + half * 64 + row;
        const int hh = hd >> 6, dd = hd & 63;
        *(bf16x8*)(v_out + ((size_t)(bb * 8 + hh) * 64 + dd) * 2048 + sq0 + c * 8) = val;
      }
    }
    return;
  }

#pragma unroll
  for (int mf = 0; mf < 4; ++mf) {
    const int m = mt * 128 + wm + mf * 16 + quad * 4;
#pragma unroll
    for (int nf = 0; nf < 4; ++nf) {
      const int n = nt * 128 + wn + nf * 16 + ln;
      const float bv = bias[n];
      const int hd = n & 511;
      const int hh = hd >> 6, dd = hd & 63;
      const int bb = m >> 11, sq = m & 2047;
      if (n < 512) {
#pragma unroll
        for (int r = 0; r < 4; ++r)
          q_out[((size_t)(bb * 8 + hh) * 2048 + sq + r) * 64 + dd] =
              f2bf((acc[mf][nf][r] + bv) * QSCALE);
      } else {
#pragma unroll
        for (int r = 0; r < 4; ++r)
          k_out[((size_t)(bb * 8 + hh) * 2048 + sq + r) * 64 + dd] = f2bf(acc[mf][nf][r] + bv);
      }
    }
  }
}

// ---------------- 128x64 bf16 MFMA GEMM (gemm1: out-proj, fp32+bias) ---------
// 512 blocks -> 2 blocks/CU (two independent barrier groups per SIMD).
__global__ __launch_bounds__(256, 3) void gemm64_k(const unsigned short* __restrict__ A,
                                                   const unsigned short* __restrict__ Bt,
                                                   const float* __restrict__ bias,
                                                   float* __restrict__ f_out) {
  __shared__ struct { unsigned short A[2][128][40], B[2][64][40]; } s;  // 30 KB

  const int t = threadIdx.x;
  const int lane = t & 63, w = t >> 6, ln = lane & 15, quad = lane >> 4;
  const int xcd = blockIdx.x & 7, loc = blockIdx.x >> 3;  // loc 0..63
  const int mt = xcd * 8 + (loc >> 3);                    // 0..63
  const int nt = loc & 7;                                 // 0..7
  const int wm = (w >> 1) * 64, wn = (w & 1) * 32;
  const int strow = t >> 2, stcol = (t & 3) * 8;

  const size_t abase = (size_t)(mt * 128 + strow) * 512 + stcol;
  const size_t bbase = (size_t)(nt * 64 + strow) * 512 + stcol;

  f32x4 acc[4][2];
#pragma unroll
  for (int i = 0; i < 4; ++i)
#pragma unroll
    for (int j = 0; j < 2; ++j) acc[i][j] = (f32x4){0.f, 0.f, 0.f, 0.f};

  bf16x8 a0 = *(const bf16x8*)(A + abase);
  bf16x8 a1 = *(const bf16x8*)(A + abase + (size_t)64 * 512);
  bf16x8 b0 = *(const bf16x8*)(Bt + bbase);
  *(bf16x8*)&s.A[0][strow][stcol] = a0;
  *(bf16x8*)&s.A[0][64 + strow][stcol] = a1;
  *(bf16x8*)&s.B[0][strow][stcol] = b0;
  __syncthreads();

  for (int it = 0; it < 16; ++it) {
    const int cur = it & 1, nxt = cur ^ 1;

    const int kn = ((it + 1) << 5) & 511;
    a0 = *(const bf16x8*)(A + abase + kn);
    a1 = *(const bf16x8*)(A + abase + (size_t)64 * 512 + kn);
    b0 = *(const bf16x8*)(Bt + bbase + kn);

    bf16x8 bfr[2];
#pragma unroll
    for (int nf = 0; nf < 2; ++nf)
      bfr[nf] = *(const bf16x8*)&s.B[cur][wn + nf * 16 + ln][quad * 8];
#pragma unroll
    for (int mf = 0; mf < 4; ++mf) {
      bf16x8 af = *(const bf16x8*)&s.A[cur][wm + mf * 16 + ln][quad * 8];
#pragma unroll
      for (int nf = 0; nf < 2; ++nf)
        acc[mf][nf] = __builtin_amdgcn_mfma_f32_16x16x32_bf16(af, bfr[nf], acc[mf][nf], 0, 0, 0);
    }

    if (it + 1 < 16) {
      *(bf16x8*)&s.A[nxt][strow][stcol] = a0;
      *(bf16x8*)&s.A[nxt][64 + strow][stcol] = a1;
      *(bf16x8*)&s.B[nxt][strow][stcol] = b0;
      __syncthreads();
    }
  }

  // epilogue (C layout: col=lane&15, row=quad*4+reg)
#pragma unroll
  for (int mf = 0; mf < 4; ++mf) {
    const int m = mt * 128 + wm + mf * 16 + quad * 4;
#pragma unroll
    for (int nf = 0; nf < 2; ++nf) {
      const int n = nt * 64 + wn + nf * 16 + ln;
      const float bv = bias[n];
#pragma unroll
      for (int r = 0; r < 4; ++r) f_out[(size_t)(m + r) * 512 + n] = acc[mf][nf][r] + bv;
    }
  }
}

// ---------------- fused flash attention, S^T orientation, dbuf, K=32 PV -----
// grid 512: bh = blk&31, qt = blk>>5. 4 waves x 32 q-rows, BN=64.
// Permuted key mapping: QK^T K-frag (h,e) loads K_lds row h*32+kperm+e*4, so
// C rows hold keys h*32+quad*8+e*4+r (16x16x32 f16 A-slot order). Masks use
// the ballot-natural layout [b][it][q][4]: bit for key 64g+32h+8quad+4e+r is
// bit (16(g&1)+8h+e) of (half(g>=2) of W_r) >> 2quad. kt loop = 8 superblocks
// x 4 (dbuf parity compile-time). QK C-operand = hoisted zero. setprio on MFMA.
__global__ __launch_bounds__(256, 2) void attn_k(const unsigned short* __restrict__ Qg,
                                                 const unsigned short* __restrict__ Kg,
                                                 const unsigned short* __restrict__ Vg,
                                                 const unsigned long long* __restrict__ Mg,
                                                 unsigned short* __restrict__ Og) {
  __shared__ unsigned short K_lds[2][64][64];  // [buf][key][d] bf16, chunk-swizzled
  __shared__ unsigned short V_lds[2][64][64];  // [buf][d][key] f16, chunk-swizzled

  const int t = threadIdx.x;
  const int w = t >> 6, lane = t & 63, ln = lane & 15, quad = lane >> 4;
  const int bh = blockIdx.x & 31, qt = blockIdx.x >> 5, bb = bh >> 3;
  const int sbase = qt * 128;

  const unsigned short* Qp = Qg + (size_t)bh * (2048 * 64);
  const unsigned short* Kp = Kg + (size_t)bh * (2048 * 64);
  const unsigned short* Vp = Vg + (size_t)bh * (64 * 2048);
  // mask base: [b][it(8)][q(2048)][4]; this thread's q-row = sbase+w*32+ln
  const unsigned long long* Mb = Mg + ((size_t)bb * 8 * 2048 + sbase + w * 32 + ln) * 4;

  bf16x8 qf[2][2];
#pragma unroll
  for (int qg = 0; qg < 2; ++qg) {
    const int qrow = sbase + w * 32 + qg * 16 + ln;
    qf[qg][0] = *(const bf16x8*)(Qp + (size_t)qrow * 64 + quad * 8);
    qf[qg][1] = *(const bf16x8*)(Qp + (size_t)qrow * 64 + 32 + quad * 8);
  }

  // ones B-frag (K=32): B[k][n]=1 iff n==0 -> lane ln==0 holds 8 ones
  const _Float16 one_h = (_Float16)((ln == 0) ? 1.0f : 0.0f);
  const f16x8 vf_one = (f16x8){one_h, one_h, one_h, one_h, one_h, one_h, one_h, one_h};

  const f32x4 zf = (f32x4){0.f, 0.f, 0.f, 0.f};  // hoisted zero C-operand

  f32x4 acc_o[2][4];
#pragma unroll
  for (int qg = 0; qg < 2; ++qg)
#pragma unroll
    for (int dg = 0; dg < 4; ++dg) acc_o[qg][dg] = zf;
  f32x4 acc_1[2] = {zf, zf};

  const int strow = t >> 2;
  const int stcol = (t & 3) * 16;       // global column base (ushorts)
  const int c0 = (t & 3) * 2;           // LDS chunk index (16B units), even
  const int gkw = (strow & 3) | (((strow >> 3) & 1) << 2);  // K write swizzle
  const int gvw = strow & 7;                                // V write swizzle

  // per-lane base pointers (linear; last-iter prefetch reads adjacent ws)
  const unsigned short* Kl = Kp + (size_t)strow * 64 + stcol;
  const unsigned short* Vl = Vp + (size_t)strow * 2048 + stcol;

  bf16x8 kr0 = *(const bf16x8*)(Kl);
  bf16x8 kr1 = *(const bf16x8*)(Kl + 8);
  bf16x8 vr0 = *(const bf16x8*)(Vl);
  bf16x8 vr1 = *(const bf16x8*)(Vl + 8);
  *(bf16x8*)&K_lds[0][strow][(c0 ^ gkw) << 3] = kr0;
  *(bf16x8*)&K_lds[0][strow][((c0 + 1) ^ gkw) << 3] = kr1;
  *(bf16x8*)&V_lds[0][strow][(c0 ^ gvw) << 3] = vr0;
  *(bf16x8*)&V_lds[0][strow][((c0 + 1) ^ gvw) << 3] = vr1;
  // masks superblock 0 (per qg: words W0,W1 | W2,W3)
  u64x2 Wlo[2], Whi[2];
#pragma unroll
  for (int qg = 0; qg < 2; ++qg) {
    Wlo[qg] = *(const u64x2*)(Mb + qg * 64);
    Whi[qg] = *(const u64x2*)(Mb + qg * 64 + 2);
  }
  __syncthreads();

  const int kperm = ((ln >> 2) << 3) + (ln & 3);             // permuted K row base
  const int gkr = (ln & 3) | (((ln >> 2) & 1) << 2);         // = K swizzle of krow
  const int gvr = ln & 7;                                    // = V swizzle of vrow
  const int kc = (quad ^ gkr) << 3;                          // phys col of chunk `quad`
  const unsigned q2 = quad << 1;                             // mask pre-shift

  for (int kts = 0; kts < 8; ++kts) {
    // prefetch next superblock's masks (wraps to it=0 at the end; unused)
    const size_t itn = (size_t)((kts < 7) ? kts + 1 : 0) * 8192;
    u64x2 nWlo[2], nWhi[2];
#pragma unroll
    for (int qg = 0; qg < 2; ++qg) {
      nWlo[qg] = *(const u64x2*)(Mb + itn + qg * 64);
      nWhi[qg] = *(const u64x2*)(Mb + itn + qg * 64 + 2);
    }

#pragma unroll
    for (int j = 0; j < 4; ++j) {
      const int kt = kts * 4 + j;
      const int cur = j & 1, nxt = cur ^ 1;  // (kts*4+j)&1 == j&1

      // next-tile global prefetch (drained at LDS writes below)
      kr0 = *(const bf16x8*)(Kl + (size_t)(kt + 1) * 4096);
      kr1 = *(const bf16x8*)(Kl + (size_t)(kt + 1) * 4096 + 8);
      vr0 = *(const bf16x8*)(Vl + (kt + 1) * 64);
      vr1 = *(const bf16x8*)(Vl + (kt + 1) * 64 + 8);

      // S^T with permuted key rows: frag f=h*2+e covers keys h*32+quad*8+e*4+r
      f32x4 sc[2][4];
      __builtin_amdgcn_s_setprio(1);
#pragma unroll
      for (int h = 0; h < 2; ++h)
#pragma unroll
        for (int e = 0; e < 2; ++e) {
          const int krow = h * 32 + kperm + e * 4;
          bf16x8 kf0 = *(const bf16x8*)&K_lds[cur][krow][kc];
          bf16x8 kf1 = *(const bf16x8*)&K_lds[cur][krow][kc ^ 32];  // chunk quad+4
#pragma unroll
          for (int qg = 0; qg < 2; ++qg) {
            f32x4 z = __builtin_amdgcn_mfma_f32_16x16x32_bf16(kf0, qf[qg][0], zf, 0, 0, 0);
            sc[qg][h * 2 + e] = __builtin_amdgcn_mfma_f32_16x16x32_bf16(kf1, qf[qg][1], z, 0, 0, 0);
          }
        }
      __builtin_amdgcn_s_setprio(0);

      // hoist V-frags (b128): B[k=quad*8+j][n=d] = V_lds[d][h*32+quad*8]
      f16x8 vfa[2][4];
#pragma unroll
      for (int h = 0; h < 2; ++h)
#pragma unroll
        for (int dg = 0; dg < 4; ++dg)
          vfa[h][dg] = *(const f16x8*)&V_lds[cur][dg * 16 + ln][((h * 4 + quad) ^ gvr) << 3];

      // mask decode (ballot-natural layout) + exp2 -> P, packed cvt
      f16x8 pa[2][2];
#pragma unroll
      for (int qg = 0; qg < 2; ++qg) {
        const unsigned s0 = (unsigned)(Wlo[qg][0] >> (j >= 2 ? 32 : 0)) >> q2;
        const unsigned s1 = (unsigned)(Wlo[qg][1] >> (j >= 2 ? 32 : 0)) >> q2;
        const unsigned s2 = (unsigned)(Whi[qg][0] >> (j >= 2 ? 32 : 0)) >> q2;
        const unsigned s3 = (unsigned)(Whi[qg][1] >> (j >= 2 ? 32 : 0)) >> q2;
#pragma unroll
        for (int h = 0; h < 2; ++h) {
          float p[8];
#pragma unroll
          for (int e = 0; e < 2; ++e) {
            const int pos = (j & 1) * 16 + h * 8 + e;
            p[e * 4 + 0] =
                EXP2F(__int_as_float(__float_as_int(sc[qg][h * 2 + e][0]) & sbit(s0, pos)));
            p[e * 4 + 1] =
                EXP2F(__int_as_float(__float_as_int(sc[qg][h * 2 + e][1]) & sbit(s1, pos)));
            p[e * 4 + 2] =
                EXP2F(__int_as_float(__float_as_int(sc[qg][h * 2 + e][2]) & sbit(s2, pos)));
            p[e * 4 + 3] =
                EXP2F(__int_as_float(__float_as_int(sc[qg][h * 2 + e][3]) & sbit(s3, pos)));
          }
          pa[qg][h] = pk8(p);
        }
      }

      // O += P @ V (K=32) ; lsum += P @ ones (col 0 of acc_1)
      __builtin_amdgcn_s_setprio(1);
#pragma unroll
      for (int h = 0; h < 2; ++h)
#pragma unroll
        for (int qg = 0; qg < 2; ++qg) {
#pragma unroll
          for (int dg = 0; dg < 4; ++dg)
            acc_o[qg][dg] = mfma_pv(pa[qg][h], vfa[h][dg], acc_o[qg][dg]);
          acc_1[qg] = mfma_pv(pa[qg][h], vf_one, acc_1[qg]);
        }
      __builtin_amdgcn_s_setprio(0);

      if (kt < 31) {
        *(bf16x8*)&K_lds[nxt][strow][(c0 ^ gkw) << 3] = kr0;
        *(bf16x8*)&K_lds[nxt][strow][((c0 + 1) ^ gkw) << 3] = kr1;
        *(bf16x8*)&V_lds[nxt][strow][(c0 ^ gvw) << 3] = vr0;
        *(bf16x8*)&V_lds[nxt][strow][((c0 + 1) ^ gvw) << 3] = vr1;
        __syncthreads();
      }
    }
    Wlo[0] = nWlo[0]; Wlo[1] = nWlo[1];
    Whi[0] = nWhi[0]; Whi[1] = nWhi[1];
  }

  // epilogue: lsum for row q=quad*4+r lives in acc_1[qg][r] at lanes ln==0
  unsigned short* Op = Og + (size_t)bb * 2048 * 512 + (size_t)(bh & 7) * 64;
#pragma unroll
  for (int qg = 0; qg < 2; ++qg)
#pragma unroll
    for (int r = 0; r < 4; ++r) {
      const float inv = 1.0f / __shfl(acc_1[qg][r], quad * 16);
      const int sq = sbase + w * 32 + qg * 16 + quad * 4 + r;
#pragma unroll
      for (int dg = 0; dg < 4; ++dg)
        Op[(size_t)sq * 512 + dg * 16 + ln] = f2bf(acc_o[qg][dg][r] * inv);
    }
}

// ---------------------------------------------------------------------------
extern "C" void kernel_launch(void* const* d_in, const int* in_sizes, int n_in, void* d_out,
                              int out_size, void* d_ws, size_t ws_size, hipStream_t stream) {
  const float* x = (const float*)d_in[0];
  const float* adj = (const float*)d_in[1];
  const float* wqkv = (const float*)d_in[2];
  const float* bqkv = (const float*)d_in[3];
  const float* outw = (const float*)d_in[4];
  const float* outb = (const float*)d_in[5];
  float* out = (float*)d_out;

  char* ws = (char*)d_ws;
  unsigned short* x_bf = (unsigned short*)(ws);                      //  8.0 MB
  unsigned short* wqkv_bf = (unsigned short*)(ws + 8388608);         //  1.5 MB
  unsigned short* outw_bf = (unsigned short*)(ws + 9961472);         //  0.5 MB
  unsigned long long* abits = (unsigned long long*)(ws + 10485760);  //  2.0 MB [b][it][q][4]
  unsigned short* Qb = (unsigned short*)(ws + 27262976);             //  8.0 MB (b,h,s,d) bf16
  unsigned short* Kb = (unsigned short*)(ws + 35651584);             //  8.0 MB (b,h,s,d) bf16
  unsigned short* Vb = (unsigned short*)(ws + 44040192);             //  8.0 MB (b,h,d,s) f16
  unsigned short* Ob = (unsigned short*)(ws + 52428800);             //  8.0 MB (b,s,e) bf16

  prep_k<<<7168, 256, 0, stream>>>(x, x_bf, wqkv, wqkv_bf, outw, outw_bf, adj, abits);

  gemm128_k<<<768, 256, 0, stream>>>(x_bf, wqkv_bf, bqkv, 512, 12, Qb, Kb, Vb);

  attn_k<<<512, 256, 0, stream>>>(Qb, Kb, Vb, abits, Ob);

  gemm64_k<<<512, 256, 0, stream>>>(Ob, outw_bf, outb, out);
}